// Round 13
// baseline (298.264 us; speedup 1.0000x reference)
//
#include <hip/hip_runtime.h>
#include <math.h>

#define NN 100000
#define NE 1600000
#define NG 64
#define F  128

constexpr int NBUCK = (NN + 127) / 128;     // 782 buckets of 128 nodes
constexpr int NBLK  = 256;                  // hist/place blocks: 1/CU
constexpr int EPB   = (NE + NBLK - 1) / NBLK;  // 6250 edges per block
constexpr int BCAP  = 3072;                 // LDS packed-pair cap per bucket (mean 2046)

typedef __bf16 bf16x8 __attribute__((ext_vector_type(8)));
typedef float  f32x4  __attribute__((ext_vector_type(4)));
typedef float  f32x2  __attribute__((ext_vector_type(2)));

__device__ __forceinline__ float b2f(unsigned short u) {
    union { unsigned i; float f; } v; v.i = ((unsigned)u) << 16; return v.f;
}
__device__ __forceinline__ unsigned short f2b(float f) {
    union { float f; unsigned i; } v; v.f = f;
    unsigned i = v.i;
    return (unsigned short)((i + 0x7fffu + ((i >> 16) & 1u)) >> 16);  // RNE
}

// ---------------- sort pipeline 1: per-block bucket histogram (LDS, dense write) --------
__global__ __launch_bounds__(256) void k_hist(const int* __restrict__ dst, int* __restrict__ histg) {
    __shared__ int h[NBUCK];
    int blk = blockIdx.x, t = threadIdx.x;
    for (int b = t; b < NBUCK; b += 256) h[b] = 0;
    __syncthreads();
    int s0 = blk * EPB, s1 = min(s0 + EPB, NE);
    for (int e = s0 + t; e < s1; e += 256) {
        int d = __builtin_nontemporal_load(&dst[e]);
        atomicAdd(&h[d >> 7], 1);
    }
    __syncthreads();
    for (int b = t; b < NBUCK; b += 256) histg[(size_t)blk * NBUCK + b] = h[b];
}

// ---------------- sort pipeline 2: per-bucket scan over NBLK blocks ----------------
__global__ __launch_bounds__(NBLK) void k_boff(const int* __restrict__ histg, int* __restrict__ offs,
                                               int* __restrict__ tot) {
    __shared__ int sh[NBLK];
    int b = blockIdx.x, t = threadIdx.x;
    int v = histg[(size_t)t * NBUCK + b];
    sh[t] = v; __syncthreads();
    for (int d = 1; d < NBLK; d <<= 1) {
        int x = (t >= d) ? sh[t - d] : 0;
        __syncthreads();
        sh[t] += x;
        __syncthreads();
    }
    offs[(size_t)b * NBLK + t] = sh[t] - v;   // exclusive over blocks
    if (t == NBLK - 1) tot[b] = sh[t];
}

// ---------------- sort pipeline 3: exclusive scan of bucket totals (pair layout) --------
__global__ __launch_bounds__(1024) void k_scanb(const int* __restrict__ tot, int* __restrict__ base) {
    __shared__ int sh[1024];
    int t = threadIdx.x;
    int v = (t < NBUCK) ? tot[t] : 0;
    sh[t] = v; __syncthreads();
    for (int d = 1; d < 1024; d <<= 1) {
        int x = (t >= d) ? sh[t - d] : 0;
        __syncthreads();
        sh[t] += x;
        __syncthreads();
    }
    if (t < NBUCK) base[t] = sh[t] - v;      // exclusive
    if (t == NBUCK - 1) base[NBUCK] = sh[t]; // = NE
}

// ---------------- sort pipeline 4: place packed (src<<7|local) bucket-partitioned --------
__global__ __launch_bounds__(256) void k_place(const int* __restrict__ src, const int* __restrict__ dst,
                                               const int* __restrict__ offs, const int* __restrict__ base,
                                               unsigned* __restrict__ pair) {
    __shared__ int cur[NBUCK];
    int blk = blockIdx.x, t = threadIdx.x;
    for (int b = t; b < NBUCK; b += 256) cur[b] = base[b] + offs[(size_t)b * NBLK + blk];
    __syncthreads();
    int s0 = blk * EPB, s1 = min(s0 + EPB, NE);
    for (int e = s0 + t; e < s1; e += 256) {
        int d = __builtin_nontemporal_load(&dst[e]);
        int s = __builtin_nontemporal_load(&src[e]);
        int pos = atomicAdd(&cur[d >> 7], 1);
        pair[pos] = ((unsigned)s << 7) | (unsigned)(d & 127);
    }
}

// ---------------- sort pipeline 5a: per-node degrees, dinv, per-bucket padded totals ----
__global__ __launch_bounds__(256) void k_cnt(const unsigned* __restrict__ pair, const int* __restrict__ base,
                                             float* __restrict__ dinv, int* __restrict__ deg,
                                             int* __restrict__ ptot) {
    __shared__ int c[128];
    __shared__ int red[256];
    int b = blockIdx.x, t = threadIdx.x;
    int s0 = base[b], n = base[b + 1] - s0;
    if (t < 128) c[t] = 0;
    __syncthreads();
    for (int i = t; i < n; i += 256) atomicAdd(&c[pair[s0 + i] & 127u], 1);
    __syncthreads();
    int g0 = b * 128;
    int pd = 0;
    if (t < 128) {
        int d = c[t];
        if (g0 + t < NN) { deg[g0 + t] = d; dinv[g0 + t] = rsqrtf((float)d + 1.0f); }
        pd = (d + 15) & ~15;
    }
    red[t] = pd; __syncthreads();
    for (int dd = 128; dd > 0; dd >>= 1) { if (t < dd) red[t] += red[t + dd]; __syncthreads(); }
    if (t == 0) ptot[b] = red[0];
}

// ---------------- sort pipeline 5b: exclusive scan of padded bucket totals ----------------
__global__ __launch_bounds__(1024) void k_scanp(const int* __restrict__ ptot, int* __restrict__ pbase) {
    __shared__ int sh[1024];
    int t = threadIdx.x;
    int v = (t < NBUCK) ? ptot[t] : 0;
    sh[t] = v; __syncthreads();
    for (int d = 1; d < 1024; d <<= 1) {
        int x = (t >= d) ? sh[t - d] : 0;
        __syncthreads();
        sh[t] += x;
        __syncthreads();
    }
    if (t < NBUCK) pbase[t] = sh[t] - v;
    if (t == NBUCK - 1) pbase[NBUCK] = sh[t];
}

// ---------------- sort pipeline 5c: row_start (padded), col scatter, pad fill ----------
// Pads point to node NN: a dedicated all-zero fp8 row -> spmm needs NO masks.
__global__ __launch_bounds__(256) void k_fin2(const unsigned* __restrict__ pair, const int* __restrict__ base,
                                              const int* __restrict__ deg, const int* __restrict__ pbase,
                                              int* __restrict__ row_start, int* __restrict__ col) {
    __shared__ unsigned lp[BCAP];
    __shared__ int loc[129];
    __shared__ int cur[128];
    int b = blockIdx.x, t = threadIdx.x;
    int s0 = base[b], n = base[b + 1] - s0;
    int g0 = b * 128;
    if (t == 0) {
        int run = pbase[b];
        for (int i = 0; i < 128; ++i) {
            loc[i] = run;
            int d = (g0 + i < NN) ? deg[g0 + i] : 0;
            run += (d + 15) & ~15;
        }
    }
    __syncthreads();
    if (t < 128 && g0 + t < NN) row_start[g0 + t] = loc[t];
    if (b == NBUCK - 1 && t == 0) row_start[NN] = pbase[NBUCK];
    if (t < 128) cur[t] = loc[t];
    __syncthreads();
    bool lds_ok = (n <= BCAP);
    if (lds_ok) {
        for (int i = t; i < n; i += 256) lp[i] = pair[s0 + i];
        __syncthreads();
        for (int i = t; i < n; i += 256) {
            unsigned v = lp[i];
            int pos = atomicAdd(&cur[v & 127u], 1);
            col[pos] = (int)(v >> 7);
        }
    } else {
        for (int i = t; i < n; i += 256) {
            unsigned v = pair[s0 + i];
            int pos = atomicAdd(&cur[v & 127u], 1);
            col[pos] = (int)(v >> 7);
        }
    }
    __syncthreads();
    if (t < 128 && g0 + t < NN) {
        int d = deg[g0 + t];
        int pd = (d + 15) & ~15;
        int s = loc[t];
        for (int k = d; k < pd; ++k) col[s + k] = NN;   // zero-row pads
    }
}

// ---------------- W prep (all 3 layers): Wt[l][n][k] = bf16(Wl[k][n]) ----------------
__global__ __launch_bounds__(256) void k_wprep3(const float* __restrict__ W1, const float* __restrict__ W2,
                                                const float* __restrict__ W3, unsigned short* __restrict__ Wt) {
    int which = blockIdx.x >> 6;                 // 64 blocks per weight
    const float* W = (which == 0) ? W1 : (which == 1) ? W2 : W3;
    int idx = (blockIdx.x & 63) * 256 + threadIdx.x;   // 16384 per weight
    int k = idx >> 7, n = idx & 127;
    Wt[(size_t)which * F * F + n * F + k] = f2b(W[idx]);
}

// ---------------- MFMA GEMM: C8[r,:] = fp8(dinv[r] * (A[r,:] @ W)), fp32 acc ----------
template <bool FP32IN>
__global__ __launch_bounds__(256) void k_gemm_mfma(const void* __restrict__ Av,
                                                   const unsigned short* __restrict__ Wt,
                                                   const float* __restrict__ dinv,
                                                   unsigned char* __restrict__ C8) {
    __shared__ unsigned short Ws[F * F];  // 32 KB, swizzled: byte ^= (n&7)<<4
    int tid = threadIdx.x;
    int wid = tid >> 6;
    int lane = tid & 63;
    int l15 = lane & 15, l4 = lane >> 4;
    int row0 = blockIdx.x * 128 + wid * 32;

    bf16x8 af[2][4];
#pragma unroll
    for (int mf = 0; mf < 2; ++mf) {
        int r = row0 + mf * 16 + l15;
        if (r > NN - 1) r = NN - 1;
        if (FP32IN) {
            const float* rp = (const float*)Av + (size_t)r * F;
#pragma unroll
            for (int ks = 0; ks < 4; ++ks) {
                float4 v0 = *(const float4*)(rp + ks * 32 + l4 * 8);
                float4 v1 = *(const float4*)(rp + ks * 32 + l4 * 8 + 4);
                bf16x8 a;
                a[0] = (__bf16)v0.x; a[1] = (__bf16)v0.y; a[2] = (__bf16)v0.z; a[3] = (__bf16)v0.w;
                a[4] = (__bf16)v1.x; a[5] = (__bf16)v1.y; a[6] = (__bf16)v1.z; a[7] = (__bf16)v1.w;
                af[mf][ks] = a;
            }
        } else {
            const unsigned short* rp = (const unsigned short*)Av + (size_t)r * F;
#pragma unroll
            for (int ks = 0; ks < 4; ++ks)
                af[mf][ks] = *(const bf16x8*)(rp + ks * 32 + l4 * 8);
        }
    }

#pragma unroll
    for (int p = 0; p < 8; ++p) {
        int idx16 = p * 256 + tid;          // 16-byte unit index, 2048 total
        int n = idx16 >> 4;
        float4 v = *(const float4*)((const char*)Wt + (size_t)idx16 * 16);
        *(float4*)((char*)Ws + (((unsigned)idx16 * 16) ^ (unsigned)((n & 7) << 4))) = v;
    }
    __syncthreads();

    f32x4 acc[2][8];
#pragma unroll
    for (int mf = 0; mf < 2; ++mf)
#pragma unroll
        for (int nf = 0; nf < 8; ++nf) acc[mf][nf] = (f32x4){0.f, 0.f, 0.f, 0.f};

#pragma unroll
    for (int ks = 0; ks < 4; ++ks) {
        bf16x8 bfr[8];
#pragma unroll
        for (int nf = 0; nf < 8; ++nf) {
            int n = nf * 16 + l15;
            unsigned byte = (unsigned)(n * 256 + ks * 64 + l4 * 16) ^ (unsigned)((n & 7) << 4);
            bfr[nf] = *(const bf16x8*)((const char*)Ws + byte);
        }
#pragma unroll
        for (int nf = 0; nf < 8; ++nf) {
            acc[0][nf] = __builtin_amdgcn_mfma_f32_16x16x32_bf16(af[0][ks], bfr[nf], acc[0][nf], 0, 0, 0);
            acc[1][nf] = __builtin_amdgcn_mfma_f32_16x16x32_bf16(af[1][ks], bfr[nf], acc[1][nf], 0, 0, 0);
        }
    }

    // write C as fp8 e4m3 (HW cvt). C/D layout: col = lane&15, row = (lane>>4)*4 + reg
#pragma unroll
    for (int mf = 0; mf < 2; ++mf)
#pragma unroll
        for (int reg = 0; reg < 4; ++reg) {
            int r = row0 + mf * 16 + l4 * 4 + reg;
            if (r < NN) {
                float di = dinv[r];
#pragma unroll
                for (int nf = 0; nf < 8; ++nf) {
                    float v = di * acc[mf][nf][reg];
                    int enc = __builtin_amdgcn_cvt_pk_fp8_f32(v, v, 0, false);
                    C8[(size_t)r * F + nf * 16 + l15] = (unsigned char)(enc & 0xff);
                }
            }
        }
}

// ---------------- SpMM aggregation (fp8 8B gathers, packed f32 acc, bf16 out) ----------
// Padded CSR (pads -> zero row NN): mask-free. 64 threads = 4 edge slots x 16 lanes;
// lane covers 8 cols via one dwordx2 (8 fp8). 16 edges in flight (4 groups x 4 slots).
// float2 accumulators -> v_pk_add_f32; 8B gathers halve address math vs r11's 4B.
__global__ __launch_bounds__(64) void k_spmm(const unsigned char* __restrict__ xw8,
                                             const int* __restrict__ row_start,
                                             const int* __restrict__ col,
                                             const float* __restrict__ dinv,
                                             const float* __restrict__ bias,
                                             unsigned short* __restrict__ hout,
                                             int do_elu) {
    int i = blockIdx.x;
    int t = threadIdx.x;
    int lc = t & 15;          // col octet: cols 8*lc .. 8*lc+7
    int slot = t >> 4;        // 0..3: which edge of the quad
    int s = row_start[i], e = row_start[i + 1];
    const uint2* base = (const uint2*)xw8;   // row j = 16 uint2, at j*16 + lc
    f32x2 a0 = {0.f, 0.f}, a1 = {0.f, 0.f}, a2 = {0.f, 0.f}, a3 = {0.f, 0.f};
    for (int p = s; p < e; p += 16) {
        int j[4];
        uint2 u[4];
#pragma unroll
        for (int q = 0; q < 4; ++q) j[q] = col[p + q * 4 + slot];
#pragma unroll
        for (int q = 0; q < 4; ++q) u[q] = base[(unsigned)(j[q] * 16 + lc)];
#pragma unroll
        for (int q = 0; q < 4; ++q) {
            a0 += __builtin_amdgcn_cvt_pk_f32_fp8(u[q].x, false);
            a1 += __builtin_amdgcn_cvt_pk_f32_fp8(u[q].x, true);
            a2 += __builtin_amdgcn_cvt_pk_f32_fp8(u[q].y, false);
            a3 += __builtin_amdgcn_cvt_pk_f32_fp8(u[q].y, true);
        }
    }
    // reduce across the 4 slots (lane bits 4,5)
#pragma unroll
    for (int m = 16; m <= 32; m <<= 1) {
        a0.x += __shfl_xor(a0.x, m); a0.y += __shfl_xor(a0.y, m);
        a1.x += __shfl_xor(a1.x, m); a1.y += __shfl_xor(a1.y, m);
        a2.x += __shfl_xor(a2.x, m); a2.y += __shfl_xor(a2.y, m);
        a3.x += __shfl_xor(a3.x, m); a3.y += __shfl_xor(a3.y, m);
    }
    float di = dinv[i];
    uint2 us = base[(unsigned)(i * 16 + lc)];
    f32x2 s0 = __builtin_amdgcn_cvt_pk_f32_fp8(us.x, false);
    f32x2 s1 = __builtin_amdgcn_cvt_pk_f32_fp8(us.x, true);
    f32x2 s2 = __builtin_amdgcn_cvt_pk_f32_fp8(us.y, false);
    f32x2 s3 = __builtin_amdgcn_cvt_pk_f32_fp8(us.y, true);
    float4 b0 = *(const float4*)&bias[lc * 8];
    float4 b1 = *(const float4*)&bias[lc * 8 + 4];
    float v0 = di * (a0.x + s0.x) + b0.x;
    float v1 = di * (a0.y + s0.y) + b0.y;
    float v2 = di * (a1.x + s1.x) + b0.z;
    float v3 = di * (a1.y + s1.y) + b0.w;
    float v4 = di * (a2.x + s2.x) + b1.x;
    float v5 = di * (a2.y + s2.y) + b1.y;
    float v6 = di * (a3.x + s3.x) + b1.z;
    float v7 = di * (a3.y + s3.y) + b1.w;
    if (do_elu) {
        v0 = (v0 > 0.f) ? v0 : (__expf(v0) - 1.f);
        v1 = (v1 > 0.f) ? v1 : (__expf(v1) - 1.f);
        v2 = (v2 > 0.f) ? v2 : (__expf(v2) - 1.f);
        v3 = (v3 > 0.f) ? v3 : (__expf(v3) - 1.f);
        v4 = (v4 > 0.f) ? v4 : (__expf(v4) - 1.f);
        v5 = (v5 > 0.f) ? v5 : (__expf(v5) - 1.f);
        v6 = (v6 > 0.f) ? v6 : (__expf(v6) - 1.f);
        v7 = (v7 > 0.f) ? v7 : (__expf(v7) - 1.f);
    }
    if (slot == 0) {
        uint4 o;
        o.x = (unsigned)f2b(v0) | ((unsigned)f2b(v1) << 16);
        o.y = (unsigned)f2b(v2) | ((unsigned)f2b(v3) << 16);
        o.z = (unsigned)f2b(v4) | ((unsigned)f2b(v5) << 16);
        o.w = (unsigned)f2b(v6) | ((unsigned)f2b(v7) << 16);
        *(uint4*)&hout[(size_t)i * F + lc * 8] = o;
    }
}

// ---------------- graph boundaries by binary search ----------------
__global__ __launch_bounds__(128) void k_gstart(const int* __restrict__ batch, int* __restrict__ gstart) {
    int g = threadIdx.x;
    if (g > NG) return;
    if (g == NG) { gstart[NG] = NN; return; }
    int lo = 0, hi = NN;
    while (lo < hi) { int mid = (lo + hi) >> 1; if (batch[mid] < g) lo = mid + 1; else hi = mid; }
    gstart[g] = lo;
}

// ---------------- mean pool (partial sums, atomic combine) ----------------
__global__ __launch_bounds__(128) void k_pool(const unsigned short* __restrict__ h,
                                              const int* __restrict__ gstart,
                                              float* __restrict__ poolsum) {
    int g = blockIdx.x >> 4, q = blockIdx.x & 15;
    int c = threadIdx.x;
    int s = gstart[g], e = gstart[g + 1];
    int n = e - s;
    int per = (n + 15) >> 4;
    int ss = s + q * per;
    int ee = min(ss + per, e);
    float acc = 0.f;
    for (int i = ss; i < ee; ++i) acc += b2f(h[(size_t)i * F + c]);
    atomicAdd(&poolsum[g * F + c], acc);
}

// ---------------- final MLP ----------------
__global__ __launch_bounds__(64) void k_mlp(const float* __restrict__ poolsum, const int* __restrict__ gstart,
                                            const float* __restrict__ stats,
                                            const float* __restrict__ fw1, const float* __restrict__ fb1,
                                            const float* __restrict__ fw2, const float* __restrict__ fb2,
                                            const float* __restrict__ fw3, const float* __restrict__ fb3,
                                            float* __restrict__ out) {
    __shared__ float gv[F + 8];
    __shared__ float h1[32];
    __shared__ float h2[16];
    int g = blockIdx.x, t = threadIdx.x;
    float cntf = fmaxf((float)(gstart[g + 1] - gstart[g]), 1.0f);
    for (int c = t; c < F; c += 64) gv[c] = poolsum[g * F + c] / cntf;
    if (t < 8) gv[F + t] = stats[g * 8 + t];
    __syncthreads();
    if (t < 32) {
        float a = fb1[t];
        for (int k = 0; k < F + 8; ++k) a += gv[k] * fw1[k * 32 + t];
        h1[t] = fmaxf(a, 0.f);
    }
    __syncthreads();
    if (t < 16) {
        float a = fb2[t];
        for (int k = 0; k < 32; ++k) a += h1[k] * fw2[k * 16 + t];
        h2[t] = fmaxf(a, 0.f);
    }
    __syncthreads();
    if (t == 0) {
        float a = fb3[0];
        for (int k = 0; k < 16; ++k) a += h2[k] * fw3[k];
        out[g] = a;
    }
}

extern "C" void kernel_launch(void* const* d_in, const int* in_sizes, int n_in,
                              void* d_out, int out_size, void* d_ws, size_t ws_size,
                              hipStream_t stream) {
    const float* x     = (const float*)d_in[0];
    const int*   ei    = (const int*)d_in[1];
    const int*   batch = (const int*)d_in[2];
    const float* stats = (const float*)d_in[3];
    const float* W1 = (const float*)d_in[4];
    const float* b1 = (const float*)d_in[5];
    const float* W2 = (const float*)d_in[6];
    const float* b2 = (const float*)d_in[7];
    const float* W3 = (const float*)d_in[8];
    const float* b3 = (const float*)d_in[9];
    const float* fw1 = (const float*)d_in[10];
    const float* fb1 = (const float*)d_in[11];
    const float* fw2 = (const float*)d_in[12];
    const float* fb2 = (const float*)d_in[13];
    const float* fw3 = (const float*)d_in[14];
    const float* fb3 = (const float*)d_in[15];
    float* out = (float*)d_out;

    const int* srcp = ei;
    const int* dstp = ei + NE;

    char* w = (char*)d_ws;
    size_t off = 0;
    auto take = [&](size_t bytes) -> char* {
        char* p = w + off;
        off += (bytes + 255) & ~size_t(255);
        return p;
    };
    int*   row_start = (int*)take((size_t)(NN + 1) * 4);
    int*   col       = (int*)take((size_t)(NE + 15 * NN + 256) * 4);  // padded CSR
    float* dinv      = (float*)take((size_t)NN * 4);
    int*   deg       = (int*)take((size_t)NN * 4);
    int*   gstart    = (int*)take((size_t)(NG + 1) * 4);
    float* poolsum   = (float*)take((size_t)NG * F * 4);
    int*   histg     = (int*)take((size_t)NBLK * NBUCK * 4);
    int*   offs      = (int*)take((size_t)NBUCK * NBLK * 4);
    int*   tot       = (int*)take((size_t)NBUCK * 4);
    int*   base      = (int*)take((size_t)(NBUCK + 1) * 4);
    int*   ptot      = (int*)take((size_t)NBUCK * 4);
    int*   pbase     = (int*)take((size_t)(NBUCK + 1) * 4);
    unsigned* pair   = (unsigned*)take((size_t)NE * 4);
    unsigned short* Wt   = (unsigned short*)take((size_t)3 * F * F * 2);
    unsigned char*  bufA = (unsigned char*)take((size_t)(NN + 1) * F);   // fp8 xw + zero row
    unsigned short* bufB = (unsigned short*)take((size_t)NN * F * 2);    // bf16 h

    hipMemsetAsync(poolsum, 0, (size_t)NG * F * 4, stream);
    hipMemsetAsync(bufA + (size_t)NN * F, 0, F, stream);   // zero row for pads (fp8 +0)

    // CSR build: two-level counting sort + padded finalize
    k_hist<<<NBLK, 256, 0, stream>>>(dstp, histg);
    k_boff<<<NBUCK, NBLK, 0, stream>>>(histg, offs, tot);
    k_scanb<<<1, 1024, 0, stream>>>(tot, base);
    k_place<<<NBLK, 256, 0, stream>>>(srcp, dstp, offs, base, pair);
    k_cnt<<<NBUCK, 256, 0, stream>>>(pair, base, dinv, deg, ptot);
    k_scanp<<<1, 1024, 0, stream>>>(ptot, pbase);
    k_fin2<<<NBUCK, 256, 0, stream>>>(pair, base, deg, pbase, row_start, col);
    k_gstart<<<1, 128, 0, stream>>>(batch, gstart);
    k_wprep3<<<192, 256, 0, stream>>>(W1, W2, W3, Wt);

    const int gemm_grid = (NN + 127) / 128;

    // layer 1 (fp32 input)
    k_gemm_mfma<true><<<gemm_grid, 256, 0, stream>>>(x, Wt, dinv, bufA);
    k_spmm<<<NN, 64, 0, stream>>>(bufA, row_start, col, dinv, b1, bufB, 1);
    // layer 2
    k_gemm_mfma<false><<<gemm_grid, 256, 0, stream>>>(bufB, Wt + F * F, dinv, bufA);
    k_spmm<<<NN, 64, 0, stream>>>(bufA, row_start, col, dinv, b2, bufB, 1);
    // layer 3
    k_gemm_mfma<false><<<gemm_grid, 256, 0, stream>>>(bufB, Wt + 2 * F * F, dinv, bufA);
    k_spmm<<<NN, 64, 0, stream>>>(bufA, row_start, col, dinv, b3, bufB, 0);

    k_pool<<<NG * 16, F, 0, stream>>>(bufB, gstart, poolsum);
    k_mlp<<<NG, 64, 0, stream>>>(poolsum, gstart, stats, fw1, fb1, fw2, fb2, fw3, fb3, out);
}

// Round 14
// 270.886 us; speedup vs baseline: 1.1011x; 1.1011x over previous
//
#include <hip/hip_runtime.h>
#include <math.h>

#define NN 100000
#define NE 1600000
#define NG 64
#define F  128

constexpr int NBUCK = (NN + 127) / 128;     // 782 buckets of 128 nodes
constexpr int NBLK  = 256;                  // hist/place blocks: 1/CU
constexpr int EPB   = (NE + NBLK - 1) / NBLK;  // 6250 edges per block
constexpr int BCAP  = 3072;                 // LDS packed-pair cap per bucket (mean 2046)

typedef __bf16 bf16x8 __attribute__((ext_vector_type(8)));
typedef float  f32x4  __attribute__((ext_vector_type(4)));
typedef float  f32x2  __attribute__((ext_vector_type(2)));

__device__ __forceinline__ float b2f(unsigned short u) {
    union { unsigned i; float f; } v; v.i = ((unsigned)u) << 16; return v.f;
}
__device__ __forceinline__ unsigned short f2b(float f) {
    union { float f; unsigned i; } v; v.f = f;
    unsigned i = v.i;
    return (unsigned short)((i + 0x7fffu + ((i >> 16) & 1u)) >> 16);  // RNE
}

// In-block exclusive scan of tot[0..NBUCK) into tb[0..NBUCK). 256 threads.
__device__ __forceinline__ void scan_tot(const int* __restrict__ tot, int* tb, int* sc) {
    int t = threadIdx.x;
    int v[4]; int sum = 0;
#pragma unroll
    for (int k = 0; k < 4; ++k) {
        int b = t * 4 + k;
        v[k] = (b < NBUCK) ? tot[b] : 0;
        sum += v[k];
    }
    sc[t] = sum; __syncthreads();
    for (int d = 1; d < 256; d <<= 1) {
        int x = (t >= d) ? sc[t - d] : 0;
        __syncthreads();
        sc[t] += x;
        __syncthreads();
    }
    int run = sc[t] - sum;   // exclusive over thread chunks
#pragma unroll
    for (int k = 0; k < 4; ++k) {
        int b = t * 4 + k;
        if (b < NBUCK) tb[b] = run;
        run += v[k];
    }
    __syncthreads();
}

// ---------------- sort pipeline 1: per-block bucket histogram (LDS, dense write) --------
__global__ __launch_bounds__(256) void k_hist(const int* __restrict__ dst, int* __restrict__ histg) {
    __shared__ int h[NBUCK];
    int blk = blockIdx.x, t = threadIdx.x;
    for (int b = t; b < NBUCK; b += 256) h[b] = 0;
    __syncthreads();
    int s0 = blk * EPB, s1 = min(s0 + EPB, NE);
    for (int e = s0 + t; e < s1; e += 256) {
        int d = __builtin_nontemporal_load(&dst[e]);
        atomicAdd(&h[d >> 7], 1);
    }
    __syncthreads();
    for (int b = t; b < NBUCK; b += 256) histg[(size_t)blk * NBUCK + b] = h[b];
}

// ---------------- sort pipeline 2: per-bucket scan over NBLK blocks (+ bucket totals) ---
__global__ __launch_bounds__(NBLK) void k_boff(const int* __restrict__ histg, int* __restrict__ offs,
                                               int* __restrict__ tot) {
    __shared__ int sh[NBLK];
    int b = blockIdx.x, t = threadIdx.x;
    int v = histg[(size_t)t * NBUCK + b];
    sh[t] = v; __syncthreads();
    for (int d = 1; d < NBLK; d <<= 1) {
        int x = (t >= d) ? sh[t - d] : 0;
        __syncthreads();
        sh[t] += x;
        __syncthreads();
    }
    offs[(size_t)b * NBLK + t] = sh[t] - v;   // exclusive over blocks
    if (t == NBLK - 1) tot[b] = sh[t];
}

// ---------------- sort pipeline 3: place packed (src<<7|local); scan fused in ----------
__global__ __launch_bounds__(256) void k_place(const int* __restrict__ src, const int* __restrict__ dst,
                                               const int* __restrict__ offs, const int* __restrict__ tot,
                                               unsigned* __restrict__ pair) {
    __shared__ int sc[256];
    __shared__ int tb[NBUCK];
    __shared__ int cur[NBUCK];
    int blk = blockIdx.x, t = threadIdx.x;
    scan_tot(tot, tb, sc);
    for (int b = t; b < NBUCK; b += 256) cur[b] = tb[b] + offs[(size_t)b * NBLK + blk];
    __syncthreads();
    int s0 = blk * EPB, s1 = min(s0 + EPB, NE);
    for (int e = s0 + t; e < s1; e += 256) {
        int d = __builtin_nontemporal_load(&dst[e]);
        int s = __builtin_nontemporal_load(&src[e]);
        int pos = atomicAdd(&cur[d >> 7], 1);
        pair[pos] = ((unsigned)s << 7) | (unsigned)(d & 127);
    }
}

// ---------------- sort pipeline 4: per-bucket finalize (dinv, row_start, col) ----------
__global__ __launch_bounds__(256) void k_final(const unsigned* __restrict__ pair, const int* __restrict__ tot,
                                               float* __restrict__ dinv,
                                               int* __restrict__ row_start, int* __restrict__ col) {
    __shared__ int sc[256];
    __shared__ int tb[NBUCK];
    __shared__ unsigned lp[BCAP];
    __shared__ int c[128];
    __shared__ int loc[128];
    int b = blockIdx.x, t = threadIdx.x;
    scan_tot(tot, tb, sc);
    int s0 = tb[b];
    int n = tot[b];
    bool lds_ok = (n <= BCAP);
    if (t < 128) c[t] = 0;
    __syncthreads();
    if (lds_ok) {
        for (int i = t; i < n; i += 256) {
            unsigned v = pair[s0 + i];
            lp[i] = v;
            atomicAdd(&c[v & 127u], 1);
        }
    } else {
        for (int i = t; i < n; i += 256) atomicAdd(&c[pair[s0 + i] & 127u], 1);
    }
    __syncthreads();
    if (t == 0) {
        int run = 0;
        for (int i = 0; i < 128; ++i) { loc[i] = run; run += c[i]; }
    }
    __syncthreads();
    int g0 = b * 128;
    if (t < 128 && g0 + t < NN) {
        int deg = c[t];
        dinv[g0 + t] = rsqrtf((float)deg + 1.0f);
        row_start[g0 + t] = s0 + loc[t];
    }
    if (b == NBUCK - 1 && t == 0) row_start[NN] = NE;
    if (t < 128) c[t] = loc[t];
    __syncthreads();
    if (lds_ok) {
        for (int i = t; i < n; i += 256) {
            unsigned v = lp[i];
            int pos = atomicAdd(&c[v & 127u], 1);
            col[s0 + pos] = (int)(v >> 7);
        }
    } else {
        for (int i = t; i < n; i += 256) {
            unsigned v = pair[s0 + i];
            int pos = atomicAdd(&c[v & 127u], 1);
            col[s0 + pos] = (int)(v >> 7);
        }
    }
}

// ---------------- misc: W prep (blocks 0-191) + graph boundaries (block 192) ----------
__global__ __launch_bounds__(256) void k_misc(const float* __restrict__ W1, const float* __restrict__ W2,
                                              const float* __restrict__ W3, unsigned short* __restrict__ Wt,
                                              const int* __restrict__ batch, int* __restrict__ gstart) {
    int bid = blockIdx.x, t = threadIdx.x;
    if (bid < 192) {
        int which = bid >> 6;
        const float* W = (which == 0) ? W1 : (which == 1) ? W2 : W3;
        int idx = (bid & 63) * 256 + t;
        int k = idx >> 7, n = idx & 127;
        Wt[(size_t)which * F * F + n * F + k] = f2b(W[idx]);
    } else {
        int g = t;
        if (g > NG) return;
        if (g == NG) { gstart[NG] = NN; return; }
        int lo = 0, hi = NN;
        while (lo < hi) { int mid = (lo + hi) >> 1; if (batch[mid] < g) lo = mid + 1; else hi = mid; }
        gstart[g] = lo;
    }
}

// ---------------- MFMA GEMM: C8[r,:] = fp8(dinv[r] * (A[r,:] @ W)), fp32 acc ----------
template <bool FP32IN>
__global__ __launch_bounds__(256) void k_gemm_mfma(const void* __restrict__ Av,
                                                   const unsigned short* __restrict__ Wt,
                                                   const float* __restrict__ dinv,
                                                   unsigned char* __restrict__ C8) {
    __shared__ unsigned short Ws[F * F];  // 32 KB, swizzled: byte ^= (n&7)<<4
    int tid = threadIdx.x;
    int wid = tid >> 6;
    int lane = tid & 63;
    int l15 = lane & 15, l4 = lane >> 4;
    int row0 = blockIdx.x * 128 + wid * 32;

    bf16x8 af[2][4];
#pragma unroll
    for (int mf = 0; mf < 2; ++mf) {
        int r = row0 + mf * 16 + l15;
        if (r > NN - 1) r = NN - 1;
        if (FP32IN) {
            const float* rp = (const float*)Av + (size_t)r * F;
#pragma unroll
            for (int ks = 0; ks < 4; ++ks) {
                float4 v0 = *(const float4*)(rp + ks * 32 + l4 * 8);
                float4 v1 = *(const float4*)(rp + ks * 32 + l4 * 8 + 4);
                bf16x8 a;
                a[0] = (__bf16)v0.x; a[1] = (__bf16)v0.y; a[2] = (__bf16)v0.z; a[3] = (__bf16)v0.w;
                a[4] = (__bf16)v1.x; a[5] = (__bf16)v1.y; a[6] = (__bf16)v1.z; a[7] = (__bf16)v1.w;
                af[mf][ks] = a;
            }
        } else {
            const unsigned short* rp = (const unsigned short*)Av + (size_t)r * F;
#pragma unroll
            for (int ks = 0; ks < 4; ++ks)
                af[mf][ks] = *(const bf16x8*)(rp + ks * 32 + l4 * 8);
        }
    }

#pragma unroll
    for (int p = 0; p < 8; ++p) {
        int idx16 = p * 256 + tid;          // 16-byte unit index, 2048 total
        int n = idx16 >> 4;
        float4 v = *(const float4*)((const char*)Wt + (size_t)idx16 * 16);
        *(float4*)((char*)Ws + (((unsigned)idx16 * 16) ^ (unsigned)((n & 7) << 4))) = v;
    }
    __syncthreads();

    f32x4 acc[2][8];
#pragma unroll
    for (int mf = 0; mf < 2; ++mf)
#pragma unroll
        for (int nf = 0; nf < 8; ++nf) acc[mf][nf] = (f32x4){0.f, 0.f, 0.f, 0.f};

#pragma unroll
    for (int ks = 0; ks < 4; ++ks) {
        bf16x8 bfr[8];
#pragma unroll
        for (int nf = 0; nf < 8; ++nf) {
            int n = nf * 16 + l15;
            unsigned byte = (unsigned)(n * 256 + ks * 64 + l4 * 16) ^ (unsigned)((n & 7) << 4);
            bfr[nf] = *(const bf16x8*)((const char*)Ws + byte);
        }
#pragma unroll
        for (int nf = 0; nf < 8; ++nf) {
            acc[0][nf] = __builtin_amdgcn_mfma_f32_16x16x32_bf16(af[0][ks], bfr[nf], acc[0][nf], 0, 0, 0);
            acc[1][nf] = __builtin_amdgcn_mfma_f32_16x16x32_bf16(af[1][ks], bfr[nf], acc[1][nf], 0, 0, 0);
        }
    }

    // write C as fp8 e4m3 (HW cvt). C/D layout: col = lane&15, row = (lane>>4)*4 + reg
#pragma unroll
    for (int mf = 0; mf < 2; ++mf)
#pragma unroll
        for (int reg = 0; reg < 4; ++reg) {
            int r = row0 + mf * 16 + l4 * 4 + reg;
            if (r < NN) {
                float di = dinv[r];
#pragma unroll
                for (int nf = 0; nf < 8; ++nf) {
                    float v = di * acc[mf][nf][reg];
                    int enc = __builtin_amdgcn_cvt_pk_fp8_f32(v, v, 0, false);
                    C8[(size_t)r * F + nf * 16 + l15] = (unsigned char)(enc & 0xff);
                }
            }
        }
}

// ---------------- SpMM aggregation (fp8 gather, packed f32 acc, bf16 out) ----------
// r11 shape (proven 41.7us): 64 threads = 2 edge slots x 32 lanes; lane covers 4 cols
// via one dword (4 fp8); 16 edges in flight. NEW: f32x2 accumulators + pk-fma masks
// (2 cvt + 2 pk-fma vs 2 cvt + 4 scalar fma per dword).
__global__ __launch_bounds__(64) void k_spmm(const unsigned char* __restrict__ xw8,
                                             const int* __restrict__ row_start,
                                             const int* __restrict__ col,
                                             const float* __restrict__ dinv,
                                             const float* __restrict__ bias,
                                             unsigned short* __restrict__ hout,
                                             int do_elu) {
    int i = blockIdx.x;
    int t = threadIdx.x;
    int lc = t & 31;          // col quad: cols 4*lc .. 4*lc+3
    int slot = t >> 5;        // 0/1: which edge of the pair
    int s = row_start[i], e = row_start[i + 1];
    const unsigned* base = (const unsigned*)xw8;   // row j starts at dword j*32
    f32x2 aL = {0.f, 0.f}, aH = {0.f, 0.f};
    for (int p = s; p < e; p += 16) {
        int j[8];
        unsigned u[8];
#pragma unroll
        for (int q = 0; q < 8; ++q) {
            int pe = p + q * 2 + slot;
            j[q] = col[pe < e ? pe : p];
        }
#pragma unroll
        for (int q = 0; q < 8; ++q) u[q] = base[(unsigned)(j[q] * 32 + lc)];
#pragma unroll
        for (int q = 0; q < 8; ++q) {
            int pe = p + q * 2 + slot;
            float m = (pe < e) ? 1.f : 0.f;
            f32x2 m2 = {m, m};
            aL += m2 * __builtin_amdgcn_cvt_pk_f32_fp8(u[q], false);
            aH += m2 * __builtin_amdgcn_cvt_pk_f32_fp8(u[q], true);
        }
    }
    aL.x += __shfl_xor(aL.x, 32);
    aL.y += __shfl_xor(aL.y, 32);
    aH.x += __shfl_xor(aH.x, 32);
    aH.y += __shfl_xor(aH.y, 32);
    float di = dinv[i];
    unsigned us = base[(unsigned)(i * 32 + lc)];
    f32x2 sL = __builtin_amdgcn_cvt_pk_f32_fp8(us, false);
    f32x2 sH = __builtin_amdgcn_cvt_pk_f32_fp8(us, true);
    float4 b4 = *(const float4*)&bias[lc * 4];
    float v0 = di * (aL.x + sL.x) + b4.x;
    float v1 = di * (aL.y + sL.y) + b4.y;
    float v2 = di * (aH.x + sH.x) + b4.z;
    float v3 = di * (aH.y + sH.y) + b4.w;
    if (do_elu) {
        v0 = (v0 > 0.f) ? v0 : (__expf(v0) - 1.f);
        v1 = (v1 > 0.f) ? v1 : (__expf(v1) - 1.f);
        v2 = (v2 > 0.f) ? v2 : (__expf(v2) - 1.f);
        v3 = (v3 > 0.f) ? v3 : (__expf(v3) - 1.f);
    }
    if (slot == 0) {
        ushort4 o;
        o.x = f2b(v0); o.y = f2b(v1); o.z = f2b(v2); o.w = f2b(v3);
        *(ushort4*)&hout[(size_t)i * F + lc * 4] = o;
    }
}

// ---------------- mean pool: dense per-q partials (no atomics, no memset) ----------------
__global__ __launch_bounds__(128) void k_pool(const unsigned short* __restrict__ h,
                                              const int* __restrict__ gstart,
                                              float* __restrict__ poolpart) {
    int g = blockIdx.x >> 4, q = blockIdx.x & 15;
    int c = threadIdx.x;
    int s = gstart[g], e = gstart[g + 1];
    int n = e - s;
    int per = (n + 15) >> 4;
    int ss = s + q * per;
    int ee = min(ss + per, e);
    float acc = 0.f;
    for (int i = ss; i < ee; ++i) acc += b2f(h[(size_t)i * F + c]);
    poolpart[((size_t)q * NG + g) * F + c] = acc;
}

// ---------------- final MLP (reduces the 16 pool partials) ----------------
__global__ __launch_bounds__(64) void k_mlp(const float* __restrict__ poolpart, const int* __restrict__ gstart,
                                            const float* __restrict__ stats,
                                            const float* __restrict__ fw1, const float* __restrict__ fb1,
                                            const float* __restrict__ fw2, const float* __restrict__ fb2,
                                            const float* __restrict__ fw3, const float* __restrict__ fb3,
                                            float* __restrict__ out) {
    __shared__ float gv[F + 8];
    __shared__ float h1[32];
    __shared__ float h2[16];
    int g = blockIdx.x, t = threadIdx.x;
    float cntf = fmaxf((float)(gstart[g + 1] - gstart[g]), 1.0f);
    for (int c = t; c < F; c += 64) {
        float a = 0.f;
#pragma unroll
        for (int q = 0; q < 16; ++q) a += poolpart[((size_t)q * NG + g) * F + c];
        gv[c] = a / cntf;
    }
    if (t < 8) gv[F + t] = stats[g * 8 + t];
    __syncthreads();
    if (t < 32) {
        float a = fb1[t];
        for (int k = 0; k < F + 8; ++k) a += gv[k] * fw1[k * 32 + t];
        h1[t] = fmaxf(a, 0.f);
    }
    __syncthreads();
    if (t < 16) {
        float a = fb2[t];
        for (int k = 0; k < 32; ++k) a += h1[k] * fw2[k * 16 + t];
        h2[t] = fmaxf(a, 0.f);
    }
    __syncthreads();
    if (t == 0) {
        float a = fb3[0];
        for (int k = 0; k < 16; ++k) a += h2[k] * fw3[k];
        out[g] = a;
    }
}

extern "C" void kernel_launch(void* const* d_in, const int* in_sizes, int n_in,
                              void* d_out, int out_size, void* d_ws, size_t ws_size,
                              hipStream_t stream) {
    const float* x     = (const float*)d_in[0];
    const int*   ei    = (const int*)d_in[1];
    const int*   batch = (const int*)d_in[2];
    const float* stats = (const float*)d_in[3];
    const float* W1 = (const float*)d_in[4];
    const float* b1 = (const float*)d_in[5];
    const float* W2 = (const float*)d_in[6];
    const float* b2 = (const float*)d_in[7];
    const float* W3 = (const float*)d_in[8];
    const float* b3 = (const float*)d_in[9];
    const float* fw1 = (const float*)d_in[10];
    const float* fb1 = (const float*)d_in[11];
    const float* fw2 = (const float*)d_in[12];
    const float* fb2 = (const float*)d_in[13];
    const float* fw3 = (const float*)d_in[14];
    const float* fb3 = (const float*)d_in[15];
    float* out = (float*)d_out;

    const int* srcp = ei;
    const int* dstp = ei + NE;

    char* w = (char*)d_ws;
    size_t off = 0;
    auto take = [&](size_t bytes) -> char* {
        char* p = w + off;
        off += (bytes + 255) & ~size_t(255);
        return p;
    };
    int*   row_start = (int*)take((size_t)(NN + 1) * 4);
    int*   col       = (int*)take((size_t)NE * 4);
    float* dinv      = (float*)take((size_t)NN * 4);
    int*   gstart    = (int*)take((size_t)(NG + 1) * 4);
    float* poolpart  = (float*)take((size_t)16 * NG * F * 4);
    int*   histg     = (int*)take((size_t)NBLK * NBUCK * 4);
    int*   offs      = (int*)take((size_t)NBUCK * NBLK * 4);
    int*   tot       = (int*)take((size_t)NBUCK * 4);
    unsigned* pair   = (unsigned*)take((size_t)NE * 4);
    unsigned short* Wt   = (unsigned short*)take((size_t)3 * F * F * 2);
    unsigned char*  bufA = (unsigned char*)take((size_t)NN * F);       // fp8 xw
    unsigned short* bufB = (unsigned short*)take((size_t)NN * F * 2);  // bf16 h

    // CSR build: two-level counting sort (scans fused into consumers)
    k_hist<<<NBLK, 256, 0, stream>>>(dstp, histg);
    k_boff<<<NBUCK, NBLK, 0, stream>>>(histg, offs, tot);
    k_place<<<NBLK, 256, 0, stream>>>(srcp, dstp, offs, tot, pair);
    k_final<<<NBUCK, 256, 0, stream>>>(pair, tot, dinv, row_start, col);
    k_misc<<<193, 256, 0, stream>>>(W1, W2, W3, Wt, batch, gstart);

    const int gemm_grid = (NN + 127) / 128;

    // layer 1 (fp32 input)
    k_gemm_mfma<true><<<gemm_grid, 256, 0, stream>>>(x, Wt, dinv, bufA);
    k_spmm<<<NN, 64, 0, stream>>>(bufA, row_start, col, dinv, b1, bufB, 1);
    // layer 2
    k_gemm_mfma<false><<<gemm_grid, 256, 0, stream>>>(bufB, Wt + F * F, dinv, bufA);
    k_spmm<<<NN, 64, 0, stream>>>(bufA, row_start, col, dinv, b2, bufB, 1);
    // layer 3
    k_gemm_mfma<false><<<gemm_grid, 256, 0, stream>>>(bufB, Wt + 2 * F * F, dinv, bufA);
    k_spmm<<<NN, 64, 0, stream>>>(bufA, row_start, col, dinv, b3, bufB, 0);

    k_pool<<<NG * 16, F, 0, stream>>>(bufB, gstart, poolpart);
    k_mlp<<<NG, 64, 0, stream>>>(poolpart, gstart, stats, fw1, fb1, fw2, fb2, fw3, fb3, out);
}